// Round 6
// baseline (567.979 us; speedup 1.0000x reference)
//
#include <hip/hip_runtime.h>
#include <hip/hip_bf16.h>

#define BATCH 16384
#define HDIM  1024
#define K1    2048
#define N1    4096

typedef __attribute__((ext_vector_type(4))) float f32x4;
typedef __attribute__((ext_vector_type(8))) short short8;

__device__ __forceinline__ unsigned short f2bf(float f) {
  union { float f; unsigned u; } v; v.f = f;
  unsigned r = v.u + 0x7FFFu + ((v.u >> 16) & 1u);
  return (unsigned short)(r >> 16);
}
__device__ __forceinline__ float bf2f(unsigned short h) {
  union { unsigned u; float f; } v; v.u = ((unsigned)h) << 16; return v.f;
}
__device__ __forceinline__ float sigmoidf_(float x) {
  return 1.0f / (1.0f + __builtin_amdgcn_exp2f(x * -1.4426950408889634f));
}
__device__ __forceinline__ float tanhf_(float x) {
  float xc = fminf(fmaxf(x, -8.0f), 8.0f);
  float e = __builtin_amdgcn_exp2f(xc * 2.8853900817779268f);
  return (e - 1.0f) / (e + 1.0f);
}
__device__ __forceinline__ void async16(const void* g, void* l) {
  __builtin_amdgcn_global_load_lds((const __attribute__((address_space(1))) void*)g,
                                   (__attribute__((address_space(3))) void*)l, 16, 0, 0);
}

// ---- conversion pass: U = [x|y] bf16 (16384 x 2048) ----
__global__ void k_convU(const float* __restrict__ x, const float* __restrict__ y,
                        unsigned short* __restrict__ U) {
  const int total = BATCH * (HDIM / 4);
  for (int q = blockIdx.x * blockDim.x + threadIdx.x; q < total;
       q += gridDim.x * blockDim.x) {
    int b = q >> 8;
    int c = (q & 255) << 2;
    float4 xv = *(const float4*)(x + (long)b * HDIM + c);
    float4 yv = *(const float4*)(y + (long)b * HDIM + c);
    uint2 xo, yo;
    xo.x = (unsigned)f2bf(xv.x) | ((unsigned)f2bf(xv.y) << 16);
    xo.y = (unsigned)f2bf(xv.z) | ((unsigned)f2bf(xv.w) << 16);
    yo.x = (unsigned)f2bf(yv.x) | ((unsigned)f2bf(yv.y) << 16);
    yo.y = (unsigned)f2bf(yv.z) | ((unsigned)f2bf(yv.w) << 16);
    *(uint2*)(U + (long)b * K1 + c) = xo;
    *(uint2*)(U + (long)b * K1 + HDIM + c) = yo;
  }
}

// ---- conversion pass: permuted Wcat (4096 x 2048) + Wz bf16 ----
__global__ void k_convW(const float* __restrict__ Wih, const float* __restrict__ Whh,
                        const float* __restrict__ Wz,
                        unsigned short* __restrict__ Wcat, unsigned short* __restrict__ Wzb) {
  const int stride = gridDim.x * blockDim.x;
  const int totalW = N1 * (K1 / 4);
  for (int q = blockIdx.x * blockDim.x + threadIdx.x; q < totalW; q += stride) {
    int np = q >> 9;
    int kb = (q & 511) << 2;
    int B = np >> 8, w = (np >> 6) & 3, c = (np >> 4) & 3, i = np & 15;
    int h = B * 64 + w * 16 + i;
    float4 v;
    if (kb < HDIM) {
      int row = (c == 0) ? h : (c == 1) ? (HDIM + h) : (c == 2) ? (3 * HDIM + h) : (2 * HDIM + h);
      v = *(const float4*)(Wih + (long)row * HDIM + kb);
    } else if (c == 3) {
      v = make_float4(0.f, 0.f, 0.f, 0.f);
    } else {
      int row = (c == 0) ? h : (c == 1) ? (HDIM + h) : (2 * HDIM + h);
      v = *(const float4*)(Whh + (long)row * HDIM + (kb - HDIM));
    }
    uint2 o;
    o.x = (unsigned)f2bf(v.x) | ((unsigned)f2bf(v.y) << 16);
    o.y = (unsigned)f2bf(v.z) | ((unsigned)f2bf(v.w) << 16);
    *(uint2*)(Wcat + (long)np * K1 + kb) = o;
  }
  const int totalZ = HDIM * (HDIM / 4);
  for (int q = blockIdx.x * blockDim.x + threadIdx.x; q < totalZ; q += stride) {
    int n = q >> 8;
    int kb = (q & 255) << 2;
    float4 v = *(const float4*)(Wz + (long)n * HDIM + kb);
    uint2 o;
    o.x = (unsigned)f2bf(v.x) | ((unsigned)f2bf(v.y) << 16);
    o.y = (unsigned)f2bf(v.z) | ((unsigned)f2bf(v.w) << 16);
    *(uint2*)(Wzb + (long)n * HDIM + kb) = o;
  }
}

// ---- 256x256 GEMM core, m201-style phases on 4-buffer BK=32 ----
// 8 waves (2M x 4N), 4 LDS K-tile buffers (kt -> buffer kt&3), staging
// distance 3. Per kt, 2 phases; each phase:
//   {ds_read frags; stage half-K-tile(kt+3); [vmcnt(6) ph0]; s_barrier;
//    s_waitcnt lgkmcnt(0); sched_barrier; setprio(1); 16 MFMA; setprio(0)}
// KEY: reads issue BEFORE the barrier, drain AFTER it -> LDS latency and
// barrier skew overlap (m201's 62%-MfmaUtil shape). vmcnt(6) at ph0 keeps
// newest {A(kt+3),B(kt+2),A(kt+2)} in flight, forces B(kt+1)+older done =
// K-tile kt+1 staged before anyone reads it (reads come after bar(kt,1)).
// Buffer safety: reads target kt&3, in-flight stages target (kt+3)&3 != kt&3.
#define STAGE_A(TT)                                                             \
  do {                                                                          \
    const int b_ = (TT) & 3;                                                    \
    const long ko_ = (long)(TT) * 32;                                           \
    async16(gA + ko_, AsBase + b_ * 16384 + t16);                               \
    async16(gA + ko_ + (long)128 * KTOT, AsBase + b_ * 16384 + 8192 + t16);     \
  } while (0)
#define STAGE_B(TT)                                                             \
  do {                                                                          \
    const int b_ = (TT) & 3;                                                    \
    const long ko_ = (long)(TT) * 32;                                           \
    async16(gB + ko_, BsBase + b_ * 16384 + t16);                               \
    async16(gB + ko_ + (long)128 * KTOT, BsBase + b_ * 16384 + 8192 + t16);     \
  } while (0)

#define PHASE0(KT, STG, VM)                                                     \
  do {                                                                          \
    const char* Ab_ = AsBase + ((KT) & 3) * 16384;                              \
    const char* Bb_ = BsBase + ((KT) & 3) * 16384;                              \
    _Pragma("unroll") for (int n = 0; n < 4; ++n)                               \
      bf[n] = *(const short8*)(Bb_ + offB4[n]);                                 \
    _Pragma("unroll") for (int m = 0; m < 4; ++m)                               \
      af[m] = *(const short8*)(Ab_ + offA[m]);                                  \
    STG;                                                                        \
    VM;                                                                         \
    __builtin_amdgcn_s_barrier();                                               \
    asm volatile("s_waitcnt lgkmcnt(0)" ::: "memory");                          \
    __builtin_amdgcn_sched_barrier(0);                                          \
    __builtin_amdgcn_s_setprio(1);                                              \
    _Pragma("unroll") for (int m = 0; m < 4; ++m)                               \
      _Pragma("unroll") for (int n = 0; n < 4; ++n)                             \
        acc[m][n] = __builtin_amdgcn_mfma_f32_16x16x32_bf16(af[m], bf[n], acc[m][n], 0, 0, 0); \
    __builtin_amdgcn_s_setprio(0);                                              \
  } while (0)

#define PHASE1(KT, STG)                                                         \
  do {                                                                          \
    const char* Ab_ = AsBase + ((KT) & 3) * 16384;                              \
    _Pragma("unroll") for (int m = 0; m < 4; ++m)                               \
      af[m] = *(const short8*)(Ab_ + offA[4 + m]);                              \
    STG;                                                                        \
    __builtin_amdgcn_s_barrier();                                               \
    asm volatile("s_waitcnt lgkmcnt(0)" ::: "memory");                          \
    __builtin_amdgcn_sched_barrier(0);                                          \
    __builtin_amdgcn_s_setprio(1);                                              \
    _Pragma("unroll") for (int m = 0; m < 4; ++m)                               \
      _Pragma("unroll") for (int n = 0; n < 4; ++n)                             \
        acc[4 + m][n] = __builtin_amdgcn_mfma_f32_16x16x32_bf16(af[m], bf[n], acc[4 + m][n], 0, 0, 0); \
    __builtin_amdgcn_s_setprio(0);                                              \
  } while (0)

#define VM6 asm volatile("s_waitcnt vmcnt(6)" ::: "memory")
#define VM4 asm volatile("s_waitcnt vmcnt(4)" ::: "memory")
#define VM0 asm volatile("s_waitcnt vmcnt(0)" ::: "memory")
#define VMNONE ((void)0)
#define STGNONE ((void)0)

template <int KTOT>
__device__ __forceinline__ void gemm256(const unsigned short* __restrict__ A,
                                        const unsigned short* __restrict__ B,
                                        long arow0, long brow0,
                                        char* AsBase, char* BsBase,
                                        f32x4 acc[8][4]) {
  const int t = threadIdx.x;
  const int lane = t & 63;
  const int wv = t >> 6;
  const int wm = wv >> 2, wn = wv & 3;
  const int rA = lane & 15;
  const int cphys = (((lane >> 4) << 4)) ^ (((rA >> 1) & 3) << 4);
  const int t16 = t * 16;
  const int s0 = t16 ^ (((t >> 3) & 3) << 4);   // inverse-swizzled source offset
  const int r0 = s0 >> 6, c0 = s0 & 63;
  const unsigned short* gA = A + (arow0 + r0) * (long)KTOT + (c0 >> 1);
  const unsigned short* gB = B + (brow0 + r0) * (long)KTOT + (c0 >> 1);
  const int NT = KTOT / 32;

  // LDS byte offsets (within one 16KB buffer) of this wave's 12 fragments
  int offA[8], offB4[4];
#pragma unroll
  for (int m = 0; m < 8; ++m)
    offA[m] = (wm * 128 + (m >> 2) * 64 + (m & 3) * 16 + rA) * 64 + cphys;
#pragma unroll
  for (int n = 0; n < 4; ++n)
    offB4[n] = (wn * 64 + n * 16 + rA) * 64 + cphys;

  // prologue: stage K-tiles 0,1,2 in order A0,B0,A1,B1,A2,B2
#pragma unroll
  for (int tt = 0; tt < 3; ++tt) {
    STAGE_A(tt);
    STAGE_B(tt);
  }
  asm volatile("s_waitcnt vmcnt(8)" ::: "memory");  // A0,B0 landed
  __builtin_amdgcn_s_barrier();

  short8 af[4], bf[4];
#pragma unroll 1
  for (int kt = 0; kt < NT - 3; ++kt) {
    PHASE0(kt, STAGE_A(kt + 3), VM6);
    PHASE1(kt, STAGE_B(kt + 3));
  }
  PHASE0(NT - 3, STGNONE, VM4);
  PHASE1(NT - 3, STGNONE);
  PHASE0(NT - 2, STGNONE, VM0);
  PHASE1(NT - 2, STGNONE);
  PHASE0(NT - 1, STGNONE, VMNONE);
  PHASE1(NT - 1, STGNONE);
}

// ---- phase 1: fused U@Wcat^T + LEM elementwise ----
__global__ __launch_bounds__(512, 2) void k_gemm1(
    const unsigned short* __restrict__ U, const unsigned short* __restrict__ Wcat,
    const float* __restrict__ z, const float* __restrict__ dtp,
    const float* __restrict__ bih, const float* __restrict__ bhh,
    const float* __restrict__ Wdt, const float* __restrict__ bdt,
    float* __restrict__ out, unsigned short* __restrict__ znb,
    unsigned short* __restrict__ sbb) {
  __shared__ char As[65536];
  __shared__ char Bs[65536];
  const int bid = blockIdx.x;
  const int sid = (bid & 7) * 128 + (bid >> 3);  // XCD-bijective swizzle (1024 % 8 == 0)
  const int bm = sid >> 4, bn = sid & 15;
  f32x4 acc[8][4];
#pragma unroll
  for (int r = 0; r < 8; ++r)
#pragma unroll
    for (int n = 0; n < 4; ++n) acc[r][n] = (f32x4)(0.0f);

  gemm256<K1>(U, Wcat, (long)bm * 256, (long)bn * 256, As, Bs, acc);

  const int t = threadIdx.x, lane = t & 63, wv = t >> 6;
  const int wm = wv >> 2, wn = wv & 3;
  const int rA = lane & 15, q4 = (lane >> 4) << 2;
  const int h = bn * 64 + wn * 16 + rA;
  const int rowbase = bm * 256 + wm * 128;
  const float bi0 = bih[h] + bhh[h];
  const float bi1 = bih[HDIM + h] + bhh[HDIM + h];
  const float bi2 = bih[3 * HDIM + h] + bhh[2 * HDIM + h];
  const float bi3 = bih[2 * HDIM + h];
  const float wdt0 = Wdt[0], wdt1 = Wdt[1], bdt0 = bdt[0], bdt1 = bdt[1];
#pragma unroll
  for (int r = 0; r < 8; ++r) {
    const int rowblk = (r >> 2) * 64 + (r & 3) * 16;
#pragma unroll
    for (int j = 0; j < 4; ++j) {
      const int b = rowbase + rowblk + q4 + j;
      const long idx = (long)b * HDIM + h;
      const float dv = dtp[b];
      const float s1 = sigmoidf_(dv * wdt0 + bdt0);
      const float s2 = sigmoidf_(dv * wdt1 + bdt1);
      const float sbar = s1 * sigmoidf_(acc[r][0][j] + bi0);
      const float s = s2 * sigmoidf_(acc[r][1][j] + bi1);
      const float zt = tanhf_(acc[r][2][j] + bi2);
      const float iz = acc[r][3][j] + bi3;
      const float znew = (1.0f - s) * z[idx] + s * zt;
      out[(long)BATCH * HDIM + idx] = znew;  // z_new output (f32)
      out[idx] = iz;                          // park i_z in y_new slot
      znb[idx] = f2bf(znew);                  // bf16 operand for phase 2
      sbb[idx] = f2bf(sbar);
    }
  }
}

// ---- phase 2: z_new@Wz^T + y_new epilogue ----
__global__ __launch_bounds__(512, 2) void k_gemm2(
    const unsigned short* __restrict__ Zn, const unsigned short* __restrict__ Wzb,
    const unsigned short* __restrict__ sbb, const float* __restrict__ yin,
    const float* __restrict__ bz, float* __restrict__ out) {
  __shared__ char As[65536];
  __shared__ char Bs[65536];
  const int bid = blockIdx.x;
  const int sid = (bid & 7) * 32 + (bid >> 3);  // 256 % 8 == 0
  const int bm = sid >> 2, bn = sid & 3;
  f32x4 acc[8][4];
#pragma unroll
  for (int r = 0; r < 8; ++r)
#pragma unroll
    for (int n = 0; n < 4; ++n) acc[r][n] = (f32x4)(0.0f);

  gemm256<HDIM>(Zn, Wzb, (long)bm * 256, (long)bn * 256, As, Bs, acc);

  const int t = threadIdx.x, lane = t & 63, wv = t >> 6;
  const int wm = wv >> 2, wn = wv & 3;
  const int rA = lane & 15, q4 = (lane >> 4) << 2;
  const int rowbase = bm * 256 + wm * 128;
#pragma unroll
  for (int n = 0; n < 4; ++n) {
    const int hc = bn * 256 + wn * 64 + n * 16 + rA;
    const float bzv = bz[hc];
#pragma unroll
    for (int r = 0; r < 8; ++r) {
      const int rowblk = (r >> 2) * 64 + (r & 3) * 16;
#pragma unroll
      for (int j = 0; j < 4; ++j) {
        const int b = rowbase + rowblk + q4 + j;
        const long idx = (long)b * HDIM + hc;
        const float tv = tanhf_(acc[r][n][j] + bzv + out[idx]);  // out[idx] holds i_z
        const float sb = bf2f(sbb[idx]);
        out[idx] = (1.0f - sb) * yin[idx] + sb * tv;  // y_new (same addr, same thread)
      }
    }
  }
}

extern "C" void kernel_launch(void* const* d_in, const int* in_sizes, int n_in,
                              void* d_out, int out_size, void* d_ws, size_t ws_size,
                              hipStream_t stream) {
  const float* x   = (const float*)d_in[0];
  const float* y   = (const float*)d_in[1];
  const float* z   = (const float*)d_in[2];
  const float* dtp = (const float*)d_in[3];
  const float* Wih = (const float*)d_in[4];
  const float* bih = (const float*)d_in[5];
  const float* Whh = (const float*)d_in[6];
  const float* bhh = (const float*)d_in[7];
  const float* Wz  = (const float*)d_in[8];
  const float* bz  = (const float*)d_in[9];
  const float* Wdt = (const float*)d_in[10];
  const float* bdt = (const float*)d_in[11];

  char* ws = (char*)d_ws;
  unsigned short* U    = (unsigned short*)(ws);              // 67,108,864 B
  unsigned short* Wcat = (unsigned short*)(ws + 67108864);   // 16,777,216 B
  unsigned short* Wzb  = (unsigned short*)(ws + 83886080);   //  2,097,152 B
  unsigned short* Znb  = (unsigned short*)(ws + 85983232);   // 33,554,432 B
  unsigned short* Sbb  = (unsigned short*)(ws + 119537664);  // 33,554,432 B -> total 153,092,096 B
  float* out = (float*)d_out;

  k_convU<<<2048, 256, 0, stream>>>(x, y, U);
  k_convW<<<2048, 256, 0, stream>>>(Wih, Whh, Wz, Wcat, Wzb);
  k_gemm1<<<1024, 512, 0, stream>>>(U, Wcat, z, dtp, bih, bhh, Wdt, bdt, out, Znb, Sbb);
  k_gemm2<<<256, 512, 0, stream>>>(Znb, Wzb, Sbb, y, bz, out);
}

// Round 7
// 518.847 us; speedup vs baseline: 1.0947x; 1.0947x over previous
//
#include <hip/hip_runtime.h>
#include <hip/hip_bf16.h>

#define BATCH 16384
#define HDIM  1024
#define K1    2048

typedef __attribute__((ext_vector_type(4))) float f32x4;
typedef __attribute__((ext_vector_type(8))) short short8;

__device__ __forceinline__ unsigned short f2bf(float f) {
  union { float f; unsigned u; } v; v.f = f;
  unsigned r = v.u + 0x7FFFu + ((v.u >> 16) & 1u);
  return (unsigned short)(r >> 16);
}
__device__ __forceinline__ float bf2f(unsigned short h) {
  union { unsigned u; float f; } v; v.u = ((unsigned)h) << 16; return v.f;
}
__device__ __forceinline__ float sigmoidf_(float x) {
  return 1.0f / (1.0f + __builtin_amdgcn_exp2f(x * -1.4426950408889634f));
}
__device__ __forceinline__ float tanhf_(float x) {
  float xc = fminf(fmaxf(x, -8.0f), 8.0f);
  float e = __builtin_amdgcn_exp2f(xc * 2.8853900817779268f);
  return (e - 1.0f) / (e + 1.0f);
}
__device__ __forceinline__ void async16(const void* g, void* l) {
  __builtin_amdgcn_global_load_lds((const __attribute__((address_space(1))) void*)g,
                                   (__attribute__((address_space(3))) void*)l, 16, 0, 0);
}

// ---- conversion pass: U = [x|y] bf16 (16384 x 2048) ----
__global__ void k_convU(const float* __restrict__ x, const float* __restrict__ y,
                        unsigned short* __restrict__ U) {
  const int total = BATCH * (HDIM / 4);
  for (int q = blockIdx.x * blockDim.x + threadIdx.x; q < total;
       q += gridDim.x * blockDim.x) {
    int b = q >> 8;
    int c = (q & 255) << 2;
    float4 xv = *(const float4*)(x + (long)b * HDIM + c);
    float4 yv = *(const float4*)(y + (long)b * HDIM + c);
    uint2 xo, yo;
    xo.x = (unsigned)f2bf(xv.x) | ((unsigned)f2bf(xv.y) << 16);
    xo.y = (unsigned)f2bf(xv.z) | ((unsigned)f2bf(xv.w) << 16);
    yo.x = (unsigned)f2bf(yv.x) | ((unsigned)f2bf(yv.y) << 16);
    yo.y = (unsigned)f2bf(yv.z) | ((unsigned)f2bf(yv.w) << 16);
    *(uint2*)(U + (long)b * K1 + c) = xo;
    *(uint2*)(U + (long)b * K1 + HDIM + c) = yo;
  }
}

// ---- conversion: permuted Wcat (3072 x 2048) + Wzcat (1024 x 2048) ----
// Wcat n' = bn*192 + w*48 + c*16 + i -> chunk c of h = bn*64 + w*16 + i
//   c0: [W_ih[h]    | W_hh[h]   ]  (i_dt1 + h_dt1)
//   c1: [W_ih[H+h]  | W_hh[H+h] ]  (i_dt2 + h_dt2)
//   c2: [W_ih[3H+h] | W_hh[2H+h]]  (i_y   + h_y  )
// Wzcat row n = [Wz[n] | W_ih[2H+n]]  (z_new@Wz^T + i_z fused, K=2048)
__global__ void k_convW(const float* __restrict__ Wih, const float* __restrict__ Whh,
                        const float* __restrict__ Wz,
                        unsigned short* __restrict__ Wcat, unsigned short* __restrict__ Wzcat) {
  const int stride = gridDim.x * blockDim.x;
  const int totalW = 3072 * (K1 / 4);
  for (int q = blockIdx.x * blockDim.x + threadIdx.x; q < totalW; q += stride) {
    int np = q >> 9;
    int kb = (q & 511) << 2;
    int bn = np / 192; int r = np - bn * 192;
    int w = r / 48; int r2 = r - w * 48;
    int c = r2 >> 4, i = r2 & 15;
    int h = bn * 64 + w * 16 + i;
    float4 v;
    if (kb < HDIM) {
      int row = (c == 0) ? h : (c == 1) ? (HDIM + h) : (3 * HDIM + h);
      v = *(const float4*)(Wih + (long)row * HDIM + kb);
    } else {
      int row = (c == 0) ? h : (c == 1) ? (HDIM + h) : (2 * HDIM + h);
      v = *(const float4*)(Whh + (long)row * HDIM + (kb - HDIM));
    }
    uint2 o;
    o.x = (unsigned)f2bf(v.x) | ((unsigned)f2bf(v.y) << 16);
    o.y = (unsigned)f2bf(v.z) | ((unsigned)f2bf(v.w) << 16);
    *(uint2*)(Wcat + (long)np * K1 + kb) = o;
  }
  const int totalZ = HDIM * (K1 / 4);
  for (int q = blockIdx.x * blockDim.x + threadIdx.x; q < totalZ; q += stride) {
    int n = q >> 9;
    int kb = (q & 511) << 2;
    float4 v = (kb < HDIM) ? *(const float4*)(Wz + (long)n * HDIM + kb)
                           : *(const float4*)(Wih + (long)(2 * HDIM + n) * HDIM + (kb - HDIM));
    uint2 o;
    o.x = (unsigned)f2bf(v.x) | ((unsigned)f2bf(v.y) << 16);
    o.y = (unsigned)f2bf(v.z) | ((unsigned)f2bf(v.w) << 16);
    *(uint2*)(Wzcat + (long)n * K1 + kb) = o;
  }
}

// ---- GEMM core: 256-row x (NF*64)-col tile, A-only LDS, B direct-to-regs ----
// 8 waves (2M x 4N), per-wave 128 x NF*16. A staged via global_load_lds into
// 8 x 16KB LDS buffers (stage distance 6): reads of buffer b drain (MFMA
// operand dependency) two barriers before b is re-staged -> no pre-barrier
// lgkm drain; ds_read latency hides under stage-issue + barrier skew.
// B fragments load global->reg (L2-resident panels), double-buffered.
// Counted vmcnt only: steady vmcnt(10+2NF) forces stage(kt+1) complete
// before barrier(kt); never drains the pipeline. LDS XOR-swizzle (slot =
// rA&7) on A via inverse-swizzled global source.
template <int NF>
__device__ __forceinline__ void vm_steady() {
  if constexpr (NF == 3) asm volatile("s_waitcnt vmcnt(16)" ::: "memory");
  else                   asm volatile("s_waitcnt vmcnt(18)" ::: "memory");
}
template <int NF>
__device__ __forceinline__ void vm_pro() {
  if constexpr (NF == 3) asm volatile("s_waitcnt vmcnt(13)" ::: "memory");
  else                   asm volatile("s_waitcnt vmcnt(14)" ::: "memory");
}

#define STAGEA(TT)                                                        \
  do {                                                                    \
    char* bb_ = lds + ((TT) & 7) * 16384;                                 \
    const unsigned short* sa_;                                            \
    const unsigned short* sb_;                                            \
    if ((TT) < KSPLIT) {                                                  \
      sa_ = pA1a + (long)(TT) * 32;                                       \
      sb_ = pA1b + (long)(TT) * 32;                                       \
    } else {                                                              \
      sa_ = pA2a + (long)((TT) - KSPLIT) * 32;                            \
      sb_ = pA2b + (long)((TT) - KSPLIT) * 32;                            \
    }                                                                     \
    async16(sa_, bb_ + t16);                                              \
    async16(sb_, bb_ + 8192 + t16);                                       \
  } while (0)

#define ITER(BFC, BFN, KT, DOB, DOS)                                      \
  do {                                                                    \
    const char* Ab_ = lds + ((KT) & 7) * 16384;                           \
    _Pragma("unroll") for (int m_ = 0; m_ < 8; ++m_)                      \
      af[m_] = *(const short8*)(Ab_ + offA[m_]);                          \
    if (DOB) {                                                            \
      _Pragma("unroll") for (int n_ = 0; n_ < NF; ++n_)                   \
        BFN[n_] = *(const short8*)(pB[n_] + (long)((KT) + 1) * 32);       \
    }                                                                     \
    if (DOS) STAGEA((KT) + 6);                                            \
    vm_steady<NF>();                                                      \
    __builtin_amdgcn_s_barrier();                                         \
    __builtin_amdgcn_sched_barrier(0);                                    \
    __builtin_amdgcn_s_setprio(1);                                        \
    _Pragma("unroll") for (int m_ = 0; m_ < 8; ++m_)                      \
      _Pragma("unroll") for (int n_ = 0; n_ < NF; ++n_)                   \
        acc[m_][n_] = __builtin_amdgcn_mfma_f32_16x16x32_bf16(            \
            af[m_], BFC[n_], acc[m_][n_], 0, 0, 0);                       \
    __builtin_amdgcn_s_setprio(0);                                        \
  } while (0)

template <int NF, int KSPLIT>
__device__ __forceinline__ void gemm_core(
    const unsigned short* __restrict__ A1, int strA1,
    const unsigned short* __restrict__ A2, int strA2,
    const unsigned short* __restrict__ Bg,
    long arow0, long brow0, char* lds, f32x4 acc[8][NF]) {
  constexpr int NT = 64;
  const int t = threadIdx.x, lane = t & 63, wv = t >> 6;
  const int wm = wv >> 2, wn = wv & 3;
  const int rA = lane & 15;
  const int cphys = ((lane >> 4) << 4) ^ (((rA >> 1) & 3) << 4);
  const int t16 = t * 16;
  // inverse-swizzled A staging source (chunk0 at L=t16, chunk1 at L=t16+8192)
  const int s0 = t16 ^ (((t16 >> 7) & 3) << 4);
  const int r0 = s0 >> 6, c0e = (s0 & 63) >> 1;
  const unsigned short* pA1a = A1 + (arow0 + r0) * (long)strA1 + c0e;
  const unsigned short* pA1b = A1 + (arow0 + r0 + 128) * (long)strA1 + c0e;
  const unsigned short* pA2a = A2 + (arow0 + r0) * (long)strA2 + c0e;
  const unsigned short* pA2b = A2 + (arow0 + r0 + 128) * (long)strA2 + c0e;
  // B direct-load pointers (rows of Bg, K-stride 2048)
  const int bcol = (lane >> 4) << 3;
  const unsigned short* pB[NF];
#pragma unroll
  for (int n = 0; n < NF; ++n)
    pB[n] = Bg + (brow0 + wn * (NF * 16) + n * 16 + rA) * (long)K1 + bcol;
  int offA[8];
#pragma unroll
  for (int m = 0; m < 8; ++m)
    offA[m] = (wm * 128 + m * 16 + rA) * 64 + cphys;

  // prologue: stage A-tiles 0..5; load B frags(0)
#pragma unroll
  for (int tt = 0; tt < 6; ++tt) STAGEA(tt);
  short8 bfA[NF], bfB[NF];
#pragma unroll
  for (int n = 0; n < NF; ++n) bfA[n] = *(const short8*)(pB[n]);
  vm_pro<NF>();
  __builtin_amdgcn_s_barrier();

  short8 af[8];
#pragma unroll 1
  for (int kt = 0; kt < NT - 6; kt += 2) {
    ITER(bfA, bfB, kt, 1, 1);
    ITER(bfB, bfA, kt + 1, 1, 1);
  }
  ITER(bfA, bfB, NT - 6, 1, 0);
  ITER(bfB, bfA, NT - 5, 1, 0);
  ITER(bfA, bfB, NT - 4, 1, 0);
  ITER(bfB, bfA, NT - 3, 1, 0);
  ITER(bfA, bfB, NT - 2, 1, 0);
  ITER(bfB, bfA, NT - 1, 0, 0);
}

// ---- phase 1: fused U@Wcat^T + LEM elementwise (256x192 tiles) ----
__global__ __launch_bounds__(512, 2) void k_gemm1(
    const unsigned short* __restrict__ U, const unsigned short* __restrict__ Wcat,
    const float* __restrict__ z, const float* __restrict__ dtp,
    const float* __restrict__ bih, const float* __restrict__ bhh,
    const float* __restrict__ Wdt, const float* __restrict__ bdt,
    float* __restrict__ out, unsigned short* __restrict__ znb,
    unsigned short* __restrict__ sbb) {
  __shared__ char lds[131072];
  const int bid = blockIdx.x;
  const int sid = (bid & 7) * 128 + (bid >> 3);  // XCD-bijective (1024 % 8 == 0)
  const int bm = sid >> 4, bn = sid & 15;
  f32x4 acc[8][3];
#pragma unroll
  for (int m = 0; m < 8; ++m)
#pragma unroll
    for (int n = 0; n < 3; ++n) acc[m][n] = (f32x4)(0.0f);

  gemm_core<3, 64>(U, K1, U, K1, Wcat, (long)bm * 256, (long)bn * 192, lds, acc);

  const int t = threadIdx.x, lane = t & 63, wv = t >> 6;
  const int wm = wv >> 2, wn = wv & 3;
  const int rA = lane & 15, q4 = (lane >> 4) << 2;
  const int h = bn * 64 + wn * 16 + rA;
  const int rowbase = bm * 256 + wm * 128;
  const float bi0 = bih[h] + bhh[h];
  const float bi1 = bih[HDIM + h] + bhh[HDIM + h];
  const float bi2 = bih[3 * HDIM + h] + bhh[2 * HDIM + h];
  const float wdt0 = Wdt[0], wdt1 = Wdt[1], bdt0 = bdt[0], bdt1 = bdt[1];
#pragma unroll
  for (int m = 0; m < 8; ++m) {
#pragma unroll
    for (int j = 0; j < 4; ++j) {
      const int b = rowbase + m * 16 + q4 + j;
      const long idx = (long)b * HDIM + h;
      const float dv = dtp[b];
      const float s1 = sigmoidf_(dv * wdt0 + bdt0);
      const float s2 = sigmoidf_(dv * wdt1 + bdt1);
      const float sbar = s1 * sigmoidf_(acc[m][0][j] + bi0);
      const float s = s2 * sigmoidf_(acc[m][1][j] + bi1);
      const float zt = tanhf_(acc[m][2][j] + bi2);
      const float znew = (1.0f - s) * z[idx] + s * zt;
      out[(long)BATCH * HDIM + idx] = znew;  // z_new output (f32)
      znb[idx] = f2bf(znew);                  // A-left-half for phase 2
      sbb[idx] = f2bf(sbar);
    }
  }
}

// ---- phase 2: [z_new|x]@[Wz|Wih_2H]^T + y_new epilogue (256x256 tiles) ----
__global__ __launch_bounds__(512, 2) void k_gemm2(
    const unsigned short* __restrict__ Zn, const unsigned short* __restrict__ U,
    const unsigned short* __restrict__ Wzcat, const unsigned short* __restrict__ sbb,
    const float* __restrict__ yin, const float* __restrict__ bz,
    float* __restrict__ out) {
  __shared__ char lds[131072];
  const int bid = blockIdx.x;
  const int sid = (bid & 7) * 32 + (bid >> 3);  // 256 % 8 == 0
  const int bm = sid >> 2, bn = sid & 3;
  f32x4 acc[8][4];
#pragma unroll
  for (int m = 0; m < 8; ++m)
#pragma unroll
    for (int n = 0; n < 4; ++n) acc[m][n] = (f32x4)(0.0f);

  // A: kt<32 -> Znb (stride 1024), kt>=32 -> x half of U (stride 2048)
  gemm_core<4, 32>(Zn, HDIM, U, K1, Wzcat, (long)bm * 256, (long)bn * 256, lds, acc);

  const int t = threadIdx.x, lane = t & 63, wv = t >> 6;
  const int wm = wv >> 2, wn = wv & 3;
  const int rA = lane & 15, q4 = (lane >> 4) << 2;
  const int rowbase = bm * 256 + wm * 128;
#pragma unroll
  for (int n = 0; n < 4; ++n) {
    const int hc = bn * 256 + wn * 64 + n * 16 + rA;
    const float bzv = bz[hc];
#pragma unroll
    for (int m = 0; m < 8; ++m) {
#pragma unroll
      for (int j = 0; j < 4; ++j) {
        const int b = rowbase + m * 16 + q4 + j;
        const long idx = (long)b * HDIM + hc;
        const float tv = tanhf_(acc[m][n][j] + bzv);
        const float sb = bf2f(sbb[idx]);
        out[idx] = (1.0f - sb) * yin[idx] + sb * tv;  // y_new
      }
    }
  }
}

extern "C" void kernel_launch(void* const* d_in, const int* in_sizes, int n_in,
                              void* d_out, int out_size, void* d_ws, size_t ws_size,
                              hipStream_t stream) {
  const float* x   = (const float*)d_in[0];
  const float* y   = (const float*)d_in[1];
  const float* z   = (const float*)d_in[2];
  const float* dtp = (const float*)d_in[3];
  const float* Wih = (const float*)d_in[4];
  const float* bih = (const float*)d_in[5];
  const float* Whh = (const float*)d_in[6];
  const float* bhh = (const float*)d_in[7];
  const float* Wz  = (const float*)d_in[8];
  const float* bz  = (const float*)d_in[9];
  const float* Wdt = (const float*)d_in[10];
  const float* bdt = (const float*)d_in[11];

  char* ws = (char*)d_ws;
  unsigned short* U     = (unsigned short*)(ws);              // 67,108,864 B
  unsigned short* Wcat  = (unsigned short*)(ws + 67108864);   // 12,582,912 B
  unsigned short* Wzcat = (unsigned short*)(ws + 79691776);   //  4,194,304 B
  unsigned short* Znb   = (unsigned short*)(ws + 83886080);   // 33,554,432 B
  unsigned short* Sbb   = (unsigned short*)(ws + 117440512);  // 33,554,432 B -> 150,994,944 B
  float* out = (float*)d_out;

  k_convU<<<2048, 256, 0, stream>>>(x, y, U);
  k_convW<<<2048, 256, 0, stream>>>(Wih, Whh, Wz, Wcat, Wzcat);
  k_gemm1<<<1024, 512, 0, stream>>>(U, Wcat, z, dtp, bih, bhh, Wdt, bdt, out, Znb, Sbb);
  k_gemm2<<<256, 512, 0, stream>>>(Znb, U, Wzcat, Sbb, y, bz, out);
}